// Round 1
// baseline (903.361 us; speedup 1.0000x reference)
//
#include <hip/hip_runtime.h>

// ACSF descriptors: G2 (edges) + G4 (triplets) scatter-added into [N,70] f32.
//
// Output layout per atom row (70 cols):
//   cols 0..15  : G2, col = i*2 + species_src          (i = eta idx 0..7)
//   cols 16..69 : G4, col = 16 + ((e*2+l)*3+z)*3+trip  (e=eta,l=lambda,z=zeta,trip=sb+sc)
// Scatter target row species always equals the reference's mask species, so
// plain atomic scatter == masked assembly.

static __device__ __forceinline__ float fc_dev(float R) {
    // 0.5*cos(pi*R/6)+0.5 ; __cosf is plenty accurate for |arg| < ~7 rad
    const float PI_OVER_CUT = 3.14159265358979323846f / 6.0f;
    return fmaf(0.5f, __cosf(PI_OVER_CUT * R), 0.5f);
}

// One thread per edge: G2 scatter + stage (D, fc(D)) for the triplet pass.
__global__ void acsf_edges_kernel(const int* __restrict__ an,
                                  const int* __restrict__ ei,
                                  const float* __restrict__ D,
                                  const float* __restrict__ g2_etas,
                                  float2* __restrict__ edata,
                                  float* __restrict__ out,
                                  int E, int use_ws) {
    int e = blockIdx.x * blockDim.x + threadIdx.x;
    if (e >= E) return;
    float d = D[e];
    float cut2 = fc_dev(d);
    if (use_ws) edata[e] = make_float2(d, cut2);
    int src = ei[e];
    int tgt = ei[E + e];
    int as = an[src];
    int at = an[tgt];
    float d2 = d * d;
    const float* __restrict__ eta = g2_etas + (as * 2 + at) * 8;
    float* __restrict__ row = out + tgt * 70 + as;
#pragma unroll
    for (int i = 0; i < 8; ++i) {
        atomicAdd(row + 2 * i, cut2 * __expf(-eta[i] * d2));
    }
}

// One thread per triplet: G4 scatter (18 values) to the central atom's row.
__global__ void acsf_triplets_kernel(const int* __restrict__ an,
                                     const int* __restrict__ ei,
                                     const float* __restrict__ D,
                                     const float2* __restrict__ edata,
                                     const int* __restrict__ id3_ba,
                                     const int* __restrict__ id3_ca,
                                     const float* __restrict__ cosphi,
                                     const float* __restrict__ g4_etas,
                                     const float* __restrict__ g4_zetas,
                                     const float* __restrict__ g4_lmdas,
                                     float* __restrict__ out,
                                     int T, int E, int use_ws) {
    int t = blockIdx.x * blockDim.x + threadIdx.x;
    if (t >= T) return;
    int eba = id3_ba[t];
    int eca = id3_ca[t];
    if (eba <= eca) return;            // m3 dedup mask (strict >)

    float R_ba, R_ca, fba, fca;
    if (use_ws) {
        float2 a = edata[eba];
        float2 b = edata[eca];
        R_ba = a.x; fba = a.y;
        R_ca = b.x; fca = b.y;
    } else {
        R_ba = D[eba]; R_ca = D[eca];
        fba = fc_dev(R_ba); fca = fc_dev(R_ca);
    }
    if (R_ba >= 6.0f || R_ca >= 6.0f) return;   // in_range (fc->0 at 6: continuous)

    float cph = cosphi[t];
    float Rbc2 = R_ba * R_ba + R_ca * R_ca - 2.0f * R_ba * R_ca * cph;
    float Rm2 = fmaxf(Rbc2, 1e-12f);
    float R_bc = sqrtf(Rm2);
    if (R_bc >= 6.0f) return;

    int seg = ei[E + eba];             // central atom (tgt of ba edge)
    int A  = an[seg];
    int sb = an[ei[eba]];
    int sc = an[ei[eca]];
    int trip = sb + sc;                // (0,0)->0 (0,1)->1 (1,1)->2
    int k4 = A * 3 + trip;

    float cut3 = fba * fca * fc_dev(R_bc);
    float r2sum = Rm2 + R_ba * R_ba + R_ca * R_ca;

    const float* __restrict__ eta = g4_etas  + k4 * 3;
    const float* __restrict__ zet = g4_zetas + k4 * 3;
    const float* __restrict__ lmd = g4_lmdas + k4 * 2;

    float rad[3];
#pragma unroll
    for (int e2 = 0; e2 < 3; ++e2)
        rad[e2] = __expf(-eta[e2] * r2sum) * cut3;

    // cl*2^(1-z) = exp2( z*log2|1+l*c| + (1-z) );  log2f(0) = -inf -> exp2 = 0 (matches 0^z)
    float al0 = fabsf(fmaf(lmd[0], cph, 1.0f));
    float al1 = fabsf(fmaf(lmd[1], cph, 1.0f));
    float lg0 = __log2f(al0);
    float lg1 = __log2f(al1);

    float* __restrict__ row = out + seg * 70 + 16 + trip;
#pragma unroll
    for (int z = 0; z < 3; ++z) {
        float zv = zet[z];
        float base = 1.0f - zv;
        float c0 = exp2f(fmaf(zv, lg0, base));
        float c1 = exp2f(fmaf(zv, lg1, base));
#pragma unroll
        for (int e2 = 0; e2 < 3; ++e2) {
            atomicAdd(row + ((e2 * 2 + 0) * 3 + z) * 3, c0 * rad[e2]);
            atomicAdd(row + ((e2 * 2 + 1) * 3 + z) * 3, c1 * rad[e2]);
        }
    }
}

extern "C" void kernel_launch(void* const* d_in, const int* in_sizes, int n_in,
                              void* d_out, int out_size, void* d_ws, size_t ws_size,
                              hipStream_t stream) {
    const int*   an       = (const int*)d_in[0];
    const int*   ei       = (const int*)d_in[1];
    const float* D        = (const float*)d_in[2];
    const int*   id3_ba   = (const int*)d_in[3];
    const int*   id3_ca   = (const int*)d_in[4];
    const float* cosphi   = (const float*)d_in[5];
    const float* g2_etas  = (const float*)d_in[6];
    const float* g4_etas  = (const float*)d_in[7];
    const float* g4_zetas = (const float*)d_in[8];
    const float* g4_lmdas = (const float*)d_in[9];
    (void)n_in;

    int E = in_sizes[2];
    int T = in_sizes[3];
    float* out = (float*)d_out;

    int use_ws = (ws_size >= (size_t)E * sizeof(float2)) ? 1 : 0;
    float2* edata = (float2*)d_ws;

    hipMemsetAsync(d_out, 0, (size_t)out_size * sizeof(float), stream);

    const int blk = 256;
    acsf_edges_kernel<<<(E + blk - 1) / blk, blk, 0, stream>>>(
        an, ei, D, g2_etas, edata, out, E, use_ws);
    acsf_triplets_kernel<<<(T + blk - 1) / blk, blk, 0, stream>>>(
        an, ei, D, edata, id3_ba, id3_ca, cosphi,
        g4_etas, g4_zetas, g4_lmdas, out, T, E, use_ws);
}

// Round 2
// 242.728 us; speedup vs baseline: 3.7217x; 3.7217x over previous
//
#include <hip/hip_runtime.h>

// ACSF G2+G4 into [N,70] f32. Strategy: bin-then-gather to eliminate f32
// global atomics (round-1 profile: 362MB atomic write-through, VALUBusy 1.4%).
//
// ws layout: [trec: N*CAP_T float4][epack: E uint2][erec: N*CAP_E uint2]
//            [tcount: N int][ecount: N int]
// Overflow beyond CAP_* falls back to direct atomics (correct for any data).
// ws too small -> round-1 direct-atomic path.

#define CAP_T 96
#define CAP_E 64

static __device__ __forceinline__ float fc_dev(float R) {
    const float PI_OVER_CUT = 0.52359877559829887308f;  // pi/6
    return fmaf(0.5f, __cosf(PI_OVER_CUT * R), 0.5f);
}

// ---------------- binned path ----------------

// One thread per edge: stage epack, insert G2 record into tgt's bin.
__global__ void edges_bin_kernel(const int* __restrict__ an,
                                 const int* __restrict__ ei,
                                 const float* __restrict__ D,
                                 const float* __restrict__ g2_etas,
                                 uint2* __restrict__ epack,
                                 int* __restrict__ ecount,
                                 uint2* __restrict__ erec,
                                 float* __restrict__ out, int E) {
    int e = blockIdx.x * blockDim.x + threadIdx.x;
    if (e >= E) return;
    float d = D[e];
    int src = ei[e];
    int tgt = ei[E + e];
    int as = an[src];
    epack[e] = make_uint2(__float_as_uint(d), ((unsigned)tgt << 1) | (unsigned)as);
    int slot = atomicAdd(&ecount[tgt], 1);
    if (slot < CAP_E) {
        erec[(size_t)tgt * CAP_E + slot] = make_uint2(__float_as_uint(d), (unsigned)as);
    } else {  // overflow fallback: direct atomics (negligible probability)
        float cut2 = fc_dev(d), d2 = d * d;
        int at = an[tgt];
        const float* eta = g2_etas + (as * 2 + at) * 8;
        float* row = out + (size_t)tgt * 70 + as;
#pragma unroll
        for (int i = 0; i < 8; ++i)
            atomicAdd(row + 2 * i, cut2 * __expf(-eta[i] * d2));
    }
}

// One thread per triplet: mask, then insert record into central atom's bin.
__global__ void trip_bin_kernel(const uint2* __restrict__ epack,
                                const int* __restrict__ id3_ba,
                                const int* __restrict__ id3_ca,
                                const float* __restrict__ cosphi,
                                const int* __restrict__ an,
                                const float* __restrict__ g4_etas,
                                const float* __restrict__ g4_zetas,
                                const float* __restrict__ g4_lmdas,
                                int* __restrict__ tcount,
                                float4* __restrict__ trec,
                                float* __restrict__ out, int T) {
    int t = blockIdx.x * blockDim.x + threadIdx.x;
    if (t >= T) return;
    int eba = id3_ba[t];
    int eca = id3_ca[t];
    if (eba <= eca) return;                       // m3 dedup
    uint2 pb = epack[eba];
    uint2 pc = epack[eca];
    float R_ba = __uint_as_float(pb.x);
    float R_ca = __uint_as_float(pc.x);
    if (R_ba >= 6.0f || R_ca >= 6.0f) return;     // in_range (fc->0 at 6)
    float cph = cosphi[t];
    float Rbc2 = R_ba * R_ba + R_ca * R_ca - 2.0f * R_ba * R_ca * cph;
    float Rm2 = fmaxf(Rbc2, 1e-12f);
    float R_bc = sqrtf(Rm2);
    if (R_bc >= 6.0f) return;
    int seg = (int)(pb.y >> 1);
    int sb = (int)(pb.y & 1u);
    int sc = (int)(pc.y & 1u);
    int trip = sb + sc;
    int slot = atomicAdd(&tcount[seg], 1);
    if (slot < CAP_T) {
        trec[(size_t)seg * CAP_T + slot] =
            make_float4(R_ba, R_ca, cph, __int_as_float(trip));
    } else {  // overflow fallback: 18 direct atomics (negligible probability)
        int A = an[seg];
        int k4 = A * 3 + trip;
        float cut3 = fc_dev(R_ba) * fc_dev(R_ca) * fc_dev(R_bc);
        float r2sum = Rm2 + R_ba * R_ba + R_ca * R_ca;
        const float* eta = g4_etas + k4 * 3;
        const float* zet = g4_zetas + k4 * 3;
        const float* lmd = g4_lmdas + k4 * 2;
        float rad[3];
#pragma unroll
        for (int e2 = 0; e2 < 3; ++e2)
            rad[e2] = __expf(-eta[e2] * r2sum) * cut3;
        float lg0 = __log2f(fabsf(fmaf(lmd[0], cph, 1.0f)));
        float lg1 = __log2f(fabsf(fmaf(lmd[1], cph, 1.0f)));
        float* row = out + (size_t)seg * 70 + 16 + trip;
#pragma unroll
        for (int z = 0; z < 3; ++z) {
            float zv = zet[z], base = 1.0f - zv;
            float c0 = exp2f(fmaf(zv, lg0, base));
            float c1 = exp2f(fmaf(zv, lg1, base));
#pragma unroll
            for (int e2 = 0; e2 < 3; ++e2) {
                atomicAdd(row + ((e2 * 2 + 0) * 3 + z) * 3, c0 * rad[e2]);
                atomicAdd(row + ((e2 * 2 + 1) * 3 + z) * 3, c1 * rad[e2]);
            }
        }
    }
}

// One wave per atom: lane c owns one output column; loop records, write once.
__global__ __launch_bounds__(256) void gather_kernel(
        const int* __restrict__ an,
        const float* __restrict__ g2_etas,
        const float* __restrict__ g4_etas,
        const float* __restrict__ g4_zetas,
        const float* __restrict__ g4_lmdas,
        const int* __restrict__ tcount, const float4* __restrict__ trec,
        const int* __restrict__ ecount, const uint2* __restrict__ erec,
        float* __restrict__ out, int N) {
    int widx = threadIdx.x >> 6;
    int lane = threadIdx.x & 63;
    int a = blockIdx.x * 4 + widx;
    if (a >= N) return;
    int A = an[a];

    // ---- G4: lane c < 54 owns col 16 + ((e*2+l)*3+z)*3+trip ----
    int c = lane;
    int trip_c = c % 3;
    int z_c = (c / 3) % 3;
    int l_c = (c / 9) % 2;
    int e_c = c / 18;
    float eta = 0.f, zv = 0.f, lm = 0.f, base = 0.f;
    if (c < 54) {
        int k4 = A * 3 + trip_c;
        eta = g4_etas[k4 * 3 + e_c];
        zv  = g4_zetas[k4 * 3 + z_c];
        lm  = g4_lmdas[k4 * 2 + l_c];
        base = 1.0f - zv;
    }
    int n_t = min(tcount[a], CAP_T);
    const float4* rec = trec + (size_t)a * CAP_T;
    float acc = 0.0f;
    for (int b0 = 0; b0 < n_t; b0 += 64) {
        int nchunk = min(64, n_t - b0);
        float4 r = make_float4(0.f, 0.f, 0.f, 0.f);
        if (lane < nchunk) r = rec[b0 + lane];
        for (int i = 0; i < nchunk; ++i) {
            float Rba = __shfl(r.x, i);
            float Rca = __shfl(r.y, i);
            float cph = __shfl(r.z, i);
            int   tr  = __shfl(__float_as_int(r.w), i);
            float Rbc2 = Rba * Rba + Rca * Rca - 2.0f * Rba * Rca * cph;
            float Rm2 = fmaxf(Rbc2, 1e-12f);
            float Rbc = sqrtf(Rm2);
            float cut3 = fc_dev(Rba) * fc_dev(Rca) * fc_dev(Rbc);
            float r2sum = Rm2 + Rba * Rba + Rca * Rca;
            float radv = __expf(-eta * r2sum);
            float lg = __log2f(fabsf(fmaf(lm, cph, 1.0f)));
            float cl = exp2f(fmaf(zv, lg, base));
            float v = cl * radv * cut3;
            acc += (tr == trip_c) ? v : 0.0f;
        }
    }
    if (c < 54) out[(size_t)a * 70 + 16 + c] += acc;   // += catches overflow atomics

    // ---- G2: lane c < 16 owns col i*2+s (s=c&1, i=c>>1) ----
    int s_c = lane & 1;
    int i_c = lane >> 1;
    float eta2 = (lane < 16) ? g2_etas[(s_c * 2 + A) * 8 + i_c] : 0.0f;
    int n_e = min(ecount[a], CAP_E);
    const uint2* erc = erec + (size_t)a * CAP_E;
    float acc2 = 0.0f;
    for (int b0 = 0; b0 < n_e; b0 += 64) {
        int nchunk = min(64, n_e - b0);
        uint2 r = make_uint2(0u, 0u);
        if (lane < nchunk) r = erc[b0 + lane];
        for (int i = 0; i < nchunk; ++i) {
            float d  = __uint_as_float(__shfl((int)r.x, i));
            int   as = __shfl((int)r.y, i);
            float v = fc_dev(d) * __expf(-eta2 * d * d);
            acc2 += (as == s_c) ? v : 0.0f;
        }
    }
    if (lane < 16) out[(size_t)a * 70 + lane] += acc2;
}

// ---------------- fallback path (round-1 direct atomics) ----------------

__global__ void acsf_edges_kernel(const int* __restrict__ an,
                                  const int* __restrict__ ei,
                                  const float* __restrict__ D,
                                  const float* __restrict__ g2_etas,
                                  float2* __restrict__ edata,
                                  float* __restrict__ out,
                                  int E, int use_ws) {
    int e = blockIdx.x * blockDim.x + threadIdx.x;
    if (e >= E) return;
    float d = D[e];
    float cut2 = fc_dev(d);
    if (use_ws) edata[e] = make_float2(d, cut2);
    int src = ei[e];
    int tgt = ei[E + e];
    int as = an[src];
    int at = an[tgt];
    float d2 = d * d;
    const float* eta = g2_etas + (as * 2 + at) * 8;
    float* row = out + (size_t)tgt * 70 + as;
#pragma unroll
    for (int i = 0; i < 8; ++i)
        atomicAdd(row + 2 * i, cut2 * __expf(-eta[i] * d2));
}

__global__ void acsf_triplets_kernel(const int* __restrict__ an,
                                     const int* __restrict__ ei,
                                     const float* __restrict__ D,
                                     const float2* __restrict__ edata,
                                     const int* __restrict__ id3_ba,
                                     const int* __restrict__ id3_ca,
                                     const float* __restrict__ cosphi,
                                     const float* __restrict__ g4_etas,
                                     const float* __restrict__ g4_zetas,
                                     const float* __restrict__ g4_lmdas,
                                     float* __restrict__ out,
                                     int T, int E, int use_ws) {
    int t = blockIdx.x * blockDim.x + threadIdx.x;
    if (t >= T) return;
    int eba = id3_ba[t];
    int eca = id3_ca[t];
    if (eba <= eca) return;
    float R_ba, R_ca, fba, fca;
    if (use_ws) {
        float2 va = edata[eba];
        float2 vb = edata[eca];
        R_ba = va.x; fba = va.y;
        R_ca = vb.x; fca = vb.y;
    } else {
        R_ba = D[eba]; R_ca = D[eca];
        fba = fc_dev(R_ba); fca = fc_dev(R_ca);
    }
    if (R_ba >= 6.0f || R_ca >= 6.0f) return;
    float cph = cosphi[t];
    float Rbc2 = R_ba * R_ba + R_ca * R_ca - 2.0f * R_ba * R_ca * cph;
    float Rm2 = fmaxf(Rbc2, 1e-12f);
    float R_bc = sqrtf(Rm2);
    if (R_bc >= 6.0f) return;
    int seg = ei[E + eba];
    int A = an[seg];
    int sb = an[ei[eba]];
    int sc = an[ei[eca]];
    int trip = sb + sc;
    int k4 = A * 3 + trip;
    float cut3 = fba * fca * fc_dev(R_bc);
    float r2sum = Rm2 + R_ba * R_ba + R_ca * R_ca;
    const float* eta = g4_etas + k4 * 3;
    const float* zet = g4_zetas + k4 * 3;
    const float* lmd = g4_lmdas + k4 * 2;
    float rad[3];
#pragma unroll
    for (int e2 = 0; e2 < 3; ++e2)
        rad[e2] = __expf(-eta[e2] * r2sum) * cut3;
    float lg0 = __log2f(fabsf(fmaf(lmd[0], cph, 1.0f)));
    float lg1 = __log2f(fabsf(fmaf(lmd[1], cph, 1.0f)));
    float* row = out + (size_t)seg * 70 + 16 + trip;
#pragma unroll
    for (int z = 0; z < 3; ++z) {
        float zv = zet[z], bse = 1.0f - zv;
        float c0 = exp2f(fmaf(zv, lg0, bse));
        float c1 = exp2f(fmaf(zv, lg1, bse));
#pragma unroll
        for (int e2 = 0; e2 < 3; ++e2) {
            atomicAdd(row + ((e2 * 2 + 0) * 3 + z) * 3, c0 * rad[e2]);
            atomicAdd(row + ((e2 * 2 + 1) * 3 + z) * 3, c1 * rad[e2]);
        }
    }
}

// ---------------- host ----------------

extern "C" void kernel_launch(void* const* d_in, const int* in_sizes, int n_in,
                              void* d_out, int out_size, void* d_ws, size_t ws_size,
                              hipStream_t stream) {
    const int*   an       = (const int*)d_in[0];
    const int*   ei       = (const int*)d_in[1];
    const float* D        = (const float*)d_in[2];
    const int*   id3_ba   = (const int*)d_in[3];
    const int*   id3_ca   = (const int*)d_in[4];
    const float* cosphi   = (const float*)d_in[5];
    const float* g2_etas  = (const float*)d_in[6];
    const float* g4_etas  = (const float*)d_in[7];
    const float* g4_zetas = (const float*)d_in[8];
    const float* g4_lmdas = (const float*)d_in[9];
    (void)n_in;

    int N = in_sizes[0];
    int E = in_sizes[2];
    int T = in_sizes[3];
    float* out = (float*)d_out;

    // ws layout (16B-aligned trec first)
    size_t trec_b  = (size_t)N * CAP_T * sizeof(float4);
    size_t epack_b = (size_t)E * sizeof(uint2);
    size_t erec_b  = (size_t)N * CAP_E * sizeof(uint2);
    size_t cnt_b   = (size_t)N * sizeof(int) * 2;
    size_t need = trec_b + epack_b + erec_b + cnt_b;

    const int blk = 256;
    hipMemsetAsync(d_out, 0, (size_t)out_size * sizeof(float), stream);

    if (ws_size >= need) {
        char* p = (char*)d_ws;
        float4* trec  = (float4*)p;            p += trec_b;
        uint2*  epack = (uint2*)p;             p += epack_b;
        uint2*  erec  = (uint2*)p;             p += erec_b;
        int*    tcount = (int*)p;
        int*    ecount = tcount + N;
        hipMemsetAsync(tcount, 0, cnt_b, stream);

        edges_bin_kernel<<<(E + blk - 1) / blk, blk, 0, stream>>>(
            an, ei, D, g2_etas, epack, ecount, erec, out, E);
        trip_bin_kernel<<<(T + blk - 1) / blk, blk, 0, stream>>>(
            epack, id3_ba, id3_ca, cosphi, an,
            g4_etas, g4_zetas, g4_lmdas, tcount, trec, out, T);
        gather_kernel<<<(N + 3) / 4, blk, 0, stream>>>(
            an, g2_etas, g4_etas, g4_zetas, g4_lmdas,
            tcount, trec, ecount, erec, out, N);
    } else {
        int use_ws = (ws_size >= (size_t)E * sizeof(float2)) ? 1 : 0;
        float2* edata = (float2*)d_ws;
        acsf_edges_kernel<<<(E + blk - 1) / blk, blk, 0, stream>>>(
            an, ei, D, g2_etas, edata, out, E, use_ws);
        acsf_triplets_kernel<<<(T + blk - 1) / blk, blk, 0, stream>>>(
            an, ei, D, edata, id3_ba, id3_ca, cosphi,
            g4_etas, g4_zetas, g4_lmdas, out, T, E, use_ws);
    }
}

// Round 3
// 196.150 us; speedup vs baseline: 4.6055x; 1.2375x over previous
//
#include <hip/hip_runtime.h>

// ACSF G2+G4 into [N,70] f32, bin-then-gather (no f32 global atomics).
// Round-3 change: geometry (cut3, r2sum, lg0, lg1 / fc, d2) is computed
// once per record in the bin passes (one-thread-per-record, hides under
// memory latency) and the gather broadcasts records via one wave-uniform
// ds_read instead of 4-5 shfls + 7 redundant transcendentals per lane.
//
// ws: [trec: N*CAP_T float4][epack: E uint2][erec: N*CAP_E float2]
//     [tcount: N int][ecount: N int]
// Bin overflow -> direct-atomic fallback (correct for any data).

#define CAP_T 96
#define CAP_E 64

static __device__ __forceinline__ float fc_dev(float R) {
    const float PI_OVER_CUT = 0.52359877559829887308f;  // pi/6
    return fmaf(0.5f, __cosf(PI_OVER_CUT * R), 0.5f);
}

// ---------------- binned path ----------------

// One thread per edge: stage epack, insert derived G2 record {fc|spec, d2}.
__global__ void edges_bin_kernel(const int* __restrict__ an,
                                 const int* __restrict__ ei,
                                 const float* __restrict__ D,
                                 const float* __restrict__ g2_etas,
                                 uint2* __restrict__ epack,
                                 int* __restrict__ ecount,
                                 float2* __restrict__ erec,
                                 float* __restrict__ out, int E) {
    int e = blockIdx.x * blockDim.x + threadIdx.x;
    if (e >= E) return;
    float d = D[e];
    int src = ei[e];
    int tgt = ei[E + e];
    int as = an[src];
    epack[e] = make_uint2(__float_as_uint(d), ((unsigned)tgt << 1) | (unsigned)as);
    float fcv = fc_dev(d);
    float d2 = d * d;
    int slot = atomicAdd(&ecount[tgt], 1);
    if (slot < CAP_E) {
        unsigned fp = (__float_as_uint(fcv) & ~1u) | (unsigned)as;
        erec[(size_t)tgt * CAP_E + slot] = make_float2(__uint_as_float(fp), d2);
    } else {  // overflow fallback (negligible probability)
        int at = an[tgt];
        const float* eta = g2_etas + (as * 2 + at) * 8;
        float* row = out + (size_t)tgt * 70 + as;
#pragma unroll
        for (int i = 0; i < 8; ++i)
            atomicAdd(row + 2 * i, fcv * __expf(-eta[i] * d2));
    }
}

// Per surviving triplet: derived record {cut3|trip, r2sum, lg0, lg1}.
static __device__ __forceinline__ void process_triplet(
        int eba, int eca, float cph,
        const uint2* __restrict__ epack,
        const int* __restrict__ an,
        const float* __restrict__ g4_etas,
        const float* __restrict__ g4_zetas,
        const float* __restrict__ g4_lmdas,
        int* __restrict__ tcount, float4* __restrict__ trec,
        float* __restrict__ out) {
    if (eba <= eca) return;                       // m3 dedup
    uint2 pb = epack[eba];
    uint2 pc = epack[eca];
    float R_ba = __uint_as_float(pb.x);
    float R_ca = __uint_as_float(pc.x);
    if (R_ba >= 6.0f || R_ca >= 6.0f) return;     // in_range (fc->0 at 6)
    float Rbc2 = R_ba * R_ba + R_ca * R_ca - 2.0f * R_ba * R_ca * cph;
    float Rm2 = fmaxf(Rbc2, 1e-12f);
    float R_bc = sqrtf(Rm2);
    if (R_bc >= 6.0f) return;
    int seg = (int)(pb.y >> 1);
    int trip = (int)(pb.y & 1u) + (int)(pc.y & 1u);
    float cut3 = fc_dev(R_ba) * fc_dev(R_ca) * fc_dev(R_bc);
    float r2sum = Rm2 + R_ba * R_ba + R_ca * R_ca;
    float lg0 = __log2f(fabsf(fmaf(-1.0f, cph, 1.0f)));   // lambda = -1
    float lg1 = __log2f(fabsf(fmaf(+1.0f, cph, 1.0f)));   // lambda = +1
    int slot = atomicAdd(&tcount[seg], 1);
    if (slot < CAP_T) {
        unsigned cu = (__float_as_uint(cut3) & ~3u) | (unsigned)trip;
        trec[(size_t)seg * CAP_T + slot] =
            make_float4(__uint_as_float(cu), r2sum, lg0, lg1);
    } else {  // overflow fallback: 18 direct atomics (negligible probability)
        int A = an[seg];
        int k4 = A * 3 + trip;
        const float* eta = g4_etas + k4 * 3;
        const float* zet = g4_zetas + k4 * 3;
        const float* lmd = g4_lmdas + k4 * 2;
        float rad[3];
#pragma unroll
        for (int e2 = 0; e2 < 3; ++e2)
            rad[e2] = __expf(-eta[e2] * r2sum) * cut3;
        float l0 = (lmd[0] < 0.0f) ? lg0 : lg1;
        float l1 = (lmd[1] < 0.0f) ? lg0 : lg1;
        float* row = out + (size_t)seg * 70 + 16 + trip;
#pragma unroll
        for (int z = 0; z < 3; ++z) {
            float zv = zet[z], base = 1.0f - zv;
            float c0 = exp2f(fmaf(zv, l0, base));
            float c1 = exp2f(fmaf(zv, l1, base));
#pragma unroll
            for (int e2 = 0; e2 < 3; ++e2) {
                atomicAdd(row + ((e2 * 2 + 0) * 3 + z) * 3, c0 * rad[e2]);
                atomicAdd(row + ((e2 * 2 + 1) * 3 + z) * 3, c1 * rad[e2]);
            }
        }
    }
}

// Two triplets per thread (vector stream loads, 2 independent chains).
__global__ void trip_bin_kernel(const uint2* __restrict__ epack,
                                const int* __restrict__ id3_ba,
                                const int* __restrict__ id3_ca,
                                const float* __restrict__ cosphi,
                                const int* __restrict__ an,
                                const float* __restrict__ g4_etas,
                                const float* __restrict__ g4_zetas,
                                const float* __restrict__ g4_lmdas,
                                int* __restrict__ tcount,
                                float4* __restrict__ trec,
                                float* __restrict__ out, int T) {
    int i = blockIdx.x * blockDim.x + threadIdx.x;
    int t0 = i * 2;
    if (t0 >= T) return;
    if (t0 + 1 < T) {
        int2   ba = ((const int2*)id3_ba)[i];
        int2   ca = ((const int2*)id3_ca)[i];
        float2 cp = ((const float2*)cosphi)[i];
        process_triplet(ba.x, ca.x, cp.x, epack, an, g4_etas, g4_zetas,
                        g4_lmdas, tcount, trec, out);
        process_triplet(ba.y, ca.y, cp.y, epack, an, g4_etas, g4_zetas,
                        g4_lmdas, tcount, trec, out);
    } else {
        process_triplet(id3_ba[t0], id3_ca[t0], cosphi[t0], epack, an,
                        g4_etas, g4_zetas, g4_lmdas, tcount, trec, out);
    }
}

// One wave per atom; LDS-stage 64-record chunks, wave-uniform ds_read
// broadcast; lane c owns one output column; 2 transcendentals/record-lane.
__global__ __launch_bounds__(256) void gather_kernel(
        const int* __restrict__ an,
        const float* __restrict__ g2_etas,
        const float* __restrict__ g4_etas,
        const float* __restrict__ g4_zetas,
        const float* __restrict__ g4_lmdas,
        const int* __restrict__ tcount, const float4* __restrict__ trec,
        const int* __restrict__ ecount, const float2* __restrict__ erec,
        float* __restrict__ out, int N) {
    __shared__ float4 sg4[4][64];
    __shared__ float2 sg2[4][64];
    int w = threadIdx.x >> 6;
    int lane = threadIdx.x & 63;
    int a = blockIdx.x * 4 + w;
    if (a >= N) return;
    int A = an[a];

    // ---- G4: lane c < 54 owns col 16 + ((e*2+l)*3+z)*3+trip ----
    int trip_c = lane % 3;
    int z_c = (lane / 3) % 3;
    int l_c = (lane / 9) % 2;
    int e_c = lane / 18;
    float eta = 0.f, zv = 0.f, base = 1.f;
    if (lane < 54) {
        int k4 = A * 3 + trip_c;
        eta = g4_etas[k4 * 3 + e_c];
        zv  = g4_zetas[k4 * 3 + z_c];
        // lambda row: l_c==0 -> -1 (lg0), l_c==1 -> +1 (lg1) per g4_lmdas order
        float lm = g4_lmdas[k4 * 2 + l_c];
        l_c = (lm < 0.0f) ? 0 : 1;
        base = 1.0f - zv;
    }
    int n_t = min(tcount[a], CAP_T);
    const float4* rec = trec + (size_t)a * CAP_T;
    float acc = 0.0f;
    for (int b0 = 0; b0 < n_t; b0 += 64) {
        int nch = min(64, n_t - b0);
        if (lane < nch) sg4[w][lane] = rec[b0 + lane];
        for (int i = 0; i < nch; ++i) {
            float4 b = sg4[w][i];                     // uniform addr: broadcast
            unsigned cu = __float_as_uint(b.x);
            int btr = (int)(cu & 3u);
            float bc = __uint_as_float(cu & ~3u);
            float radv = __expf(-eta * b.y);
            float lg = l_c ? b.w : b.z;
            float cl = exp2f(fmaf(zv, lg, base));
            acc += (btr == trip_c) ? cl * radv * bc : 0.0f;
        }
    }
    if (lane < 54) out[(size_t)a * 70 + 16 + lane] += acc;

    // ---- G2: lane c < 16 owns col i*2+s ----
    int s_c = lane & 1;
    int i_c = lane >> 1;
    float eta2 = (lane < 16) ? g2_etas[(s_c * 2 + A) * 8 + i_c] : 0.0f;
    int n_e = min(ecount[a], CAP_E);
    const float2* erc = erec + (size_t)a * CAP_E;
    float acc2 = 0.0f;
    for (int b0 = 0; b0 < n_e; b0 += 64) {
        int nch = min(64, n_e - b0);
        if (lane < nch) sg2[w][lane] = erc[b0 + lane];
        for (int i = 0; i < nch; ++i) {
            float2 b = sg2[w][i];
            unsigned fp = __float_as_uint(b.x);
            int sp = (int)(fp & 1u);
            float fcv = __uint_as_float(fp & ~1u);
            float v = fcv * __expf(-eta2 * b.y);
            acc2 += (sp == s_c) ? v : 0.0f;
        }
    }
    if (lane < 16) out[(size_t)a * 70 + lane] += acc2;
}

// ---------------- fallback path (direct atomics) ----------------

__global__ void acsf_edges_kernel(const int* __restrict__ an,
                                  const int* __restrict__ ei,
                                  const float* __restrict__ D,
                                  const float* __restrict__ g2_etas,
                                  float2* __restrict__ edata,
                                  float* __restrict__ out,
                                  int E, int use_ws) {
    int e = blockIdx.x * blockDim.x + threadIdx.x;
    if (e >= E) return;
    float d = D[e];
    float cut2 = fc_dev(d);
    if (use_ws) edata[e] = make_float2(d, cut2);
    int src = ei[e];
    int tgt = ei[E + e];
    int as = an[src];
    int at = an[tgt];
    float d2 = d * d;
    const float* eta = g2_etas + (as * 2 + at) * 8;
    float* row = out + (size_t)tgt * 70 + as;
#pragma unroll
    for (int i = 0; i < 8; ++i)
        atomicAdd(row + 2 * i, cut2 * __expf(-eta[i] * d2));
}

__global__ void acsf_triplets_kernel(const int* __restrict__ an,
                                     const int* __restrict__ ei,
                                     const float* __restrict__ D,
                                     const float2* __restrict__ edata,
                                     const int* __restrict__ id3_ba,
                                     const int* __restrict__ id3_ca,
                                     const float* __restrict__ cosphi,
                                     const float* __restrict__ g4_etas,
                                     const float* __restrict__ g4_zetas,
                                     const float* __restrict__ g4_lmdas,
                                     float* __restrict__ out,
                                     int T, int E, int use_ws) {
    int t = blockIdx.x * blockDim.x + threadIdx.x;
    if (t >= T) return;
    int eba = id3_ba[t];
    int eca = id3_ca[t];
    if (eba <= eca) return;
    float R_ba, R_ca, fba, fca;
    if (use_ws) {
        float2 va = edata[eba];
        float2 vb = edata[eca];
        R_ba = va.x; fba = va.y;
        R_ca = vb.x; fca = vb.y;
    } else {
        R_ba = D[eba]; R_ca = D[eca];
        fba = fc_dev(R_ba); fca = fc_dev(R_ca);
    }
    if (R_ba >= 6.0f || R_ca >= 6.0f) return;
    float cph = cosphi[t];
    float Rbc2 = R_ba * R_ba + R_ca * R_ca - 2.0f * R_ba * R_ca * cph;
    float Rm2 = fmaxf(Rbc2, 1e-12f);
    float R_bc = sqrtf(Rm2);
    if (R_bc >= 6.0f) return;
    int seg = ei[E + eba];
    int A = an[seg];
    int sb = an[ei[eba]];
    int sc = an[ei[eca]];
    int trip = sb + sc;
    int k4 = A * 3 + trip;
    float cut3 = fba * fca * fc_dev(R_bc);
    float r2sum = Rm2 + R_ba * R_ba + R_ca * R_ca;
    const float* eta = g4_etas + k4 * 3;
    const float* zet = g4_zetas + k4 * 3;
    const float* lmd = g4_lmdas + k4 * 2;
    float rad[3];
#pragma unroll
    for (int e2 = 0; e2 < 3; ++e2)
        rad[e2] = __expf(-eta[e2] * r2sum) * cut3;
    float lg0 = __log2f(fabsf(fmaf(lmd[0], cph, 1.0f)));
    float lg1 = __log2f(fabsf(fmaf(lmd[1], cph, 1.0f)));
    float* row = out + (size_t)seg * 70 + 16 + trip;
#pragma unroll
    for (int z = 0; z < 3; ++z) {
        float zv = zet[z], bse = 1.0f - zv;
        float c0 = exp2f(fmaf(zv, lg0, bse));
        float c1 = exp2f(fmaf(zv, lg1, bse));
#pragma unroll
        for (int e2 = 0; e2 < 3; ++e2) {
            atomicAdd(row + ((e2 * 2 + 0) * 3 + z) * 3, c0 * rad[e2]);
            atomicAdd(row + ((e2 * 2 + 1) * 3 + z) * 3, c1 * rad[e2]);
        }
    }
}

// ---------------- host ----------------

extern "C" void kernel_launch(void* const* d_in, const int* in_sizes, int n_in,
                              void* d_out, int out_size, void* d_ws, size_t ws_size,
                              hipStream_t stream) {
    const int*   an       = (const int*)d_in[0];
    const int*   ei       = (const int*)d_in[1];
    const float* D        = (const float*)d_in[2];
    const int*   id3_ba   = (const int*)d_in[3];
    const int*   id3_ca   = (const int*)d_in[4];
    const float* cosphi   = (const float*)d_in[5];
    const float* g2_etas  = (const float*)d_in[6];
    const float* g4_etas  = (const float*)d_in[7];
    const float* g4_zetas = (const float*)d_in[8];
    const float* g4_lmdas = (const float*)d_in[9];
    (void)n_in;

    int N = in_sizes[0];
    int E = in_sizes[2];
    int T = in_sizes[3];
    float* out = (float*)d_out;

    size_t trec_b  = (size_t)N * CAP_T * sizeof(float4);
    size_t epack_b = (size_t)E * sizeof(uint2);
    size_t erec_b  = (size_t)N * CAP_E * sizeof(float2);
    size_t cnt_b   = (size_t)N * sizeof(int) * 2;
    size_t need = trec_b + epack_b + erec_b + cnt_b;

    const int blk = 256;
    hipMemsetAsync(d_out, 0, (size_t)out_size * sizeof(float), stream);

    if (ws_size >= need) {
        char* p = (char*)d_ws;
        float4* trec  = (float4*)p;            p += trec_b;
        uint2*  epack = (uint2*)p;             p += epack_b;
        float2* erec  = (float2*)p;            p += erec_b;
        int*    tcount = (int*)p;
        int*    ecount = tcount + N;
        hipMemsetAsync(tcount, 0, cnt_b, stream);

        edges_bin_kernel<<<(E + blk - 1) / blk, blk, 0, stream>>>(
            an, ei, D, g2_etas, epack, ecount, erec, out, E);
        int tthreads = (T + 1) / 2;
        trip_bin_kernel<<<(tthreads + blk - 1) / blk, blk, 0, stream>>>(
            epack, id3_ba, id3_ca, cosphi, an,
            g4_etas, g4_zetas, g4_lmdas, tcount, trec, out, T);
        gather_kernel<<<(N + 3) / 4, blk, 0, stream>>>(
            an, g2_etas, g4_etas, g4_zetas, g4_lmdas,
            tcount, trec, ecount, erec, out, N);
    } else {
        int use_ws = (ws_size >= (size_t)E * sizeof(float2)) ? 1 : 0;
        float2* edata = (float2*)d_ws;
        acsf_edges_kernel<<<(E + blk - 1) / blk, blk, 0, stream>>>(
            an, ei, D, g2_etas, edata, out, E, use_ws);
        acsf_triplets_kernel<<<(T + blk - 1) / blk, blk, 0, stream>>>(
            an, ei, D, edata, id3_ba, id3_ca, cosphi,
            g4_etas, g4_zetas, g4_lmdas, out, T, E, use_ws);
    }
}